// Round 7
// baseline (7974.605 us; speedup 1.0000x reference)
//
#include <hip/hip_runtime.h>
#include <cstdint>
#include <type_traits>

#define B_    8
#define T_    2048
#define C_    1024
#define E_    8
#define K_    2
#define CAP_  4096
#define H_    4096
#define NTOK  (B_ * T_)      // 16384
#define NSLOT (NTOK * K_)    // 32768
#define KR_   3072           // router split-GEMM K: [x_hi | x_lo | x_hi]

typedef __bf16 bf16x8 __attribute__((ext_vector_type(8)));
typedef float  f32x4  __attribute__((ext_vector_type(4)));

static __device__ __forceinline__ float b2f(unsigned short u) {
    union { float f; unsigned int i; } v; v.i = ((unsigned int)u) << 16; return v.f;
}
static __device__ __forceinline__ unsigned short f2b(float f) {
    unsigned int x = __float_as_uint(f);
    unsigned int r = (x + 0x7fffu + ((x >> 16) & 1u)) >> 16;   // RNE
    return (unsigned short)r;
}

static __device__ __forceinline__ void vm_drain() {
    asm volatile("s_waitcnt vmcnt(0)" ::: "memory");
}

// ---------------------------------------------------------------------------
// MFMA bf16 GEMM: 256x256 tile, BK=32, 512 threads (8 waves, 2Mx4N),
// ring-2 LDS K-tile buffers (64 KiB/block -> 2 blocks/CU for cross-block
// overlap of barrier/stage windows), XOR bank-swizzle on LDS (both-sides:
// pre-swizzled global_load_lds source + swizzled ds_read).
// COMPUTE is software-pipelined: B frags + first A-pair loaded, then each
// quadrant prefetches the next A-pair while MFMAing the current one.
// STAGE(t+1) issued at iter start; vmcnt(0) drain at iter end is covered by
// ~1300cy of compute >= HBM latency. One barrier per K-iter.
// A [M][Kd] bf16 row-major, BT [N][Kd] bf16 (pre-transposed). Out [M][Nld].
// Requires M%256==0, N%256==0, Kd%32==0, NT=Kd/32 >= 2, grid.x*grid.y%8==0.
// ---------------------------------------------------------------------------
template<int RELU, typename TC>
__global__ __launch_bounds__(512, 4) void gemm256_pipe(
    const unsigned short* __restrict__ A, const unsigned short* __restrict__ BT,
    const float* __restrict__ bias, TC* __restrict__ Cout,
    int Kd, int Nld, int NT,
    long sA, long sB, long sBias, long sC)
{
    extern __shared__ char smem[];   // 2 ring slots x (A 16KB | B 16KB)

    const int z = blockIdx.z;
    A    += (size_t)z * sA;
    BT   += (size_t)z * sB;
    bias += (size_t)z * sBias;
    Cout += (size_t)z * sC;

    // XCD-aware swizzle (nwg % 8 == 0 for all our grids)
    const int gx = gridDim.x;
    const int nwg = gx * gridDim.y;
    int wg = blockIdx.y * gx + blockIdx.x;
    wg = (wg & 7) * (nwg >> 3) + (wg >> 3);
    const int bm = (wg / gx) * 256;
    const int bn = (wg % gx) * 256;

    const int tid  = threadIdx.x;
    const int lane = tid & 63;
    const int wid  = tid >> 6;
    const int wrow = (wid >> 2) * 128;   // wave M offset (2 waves in M)
    const int wcol = (wid & 3) * 64;     // wave N offset (4 waves in N)
    const int fr = lane & 15;            // fragment row/col within 16
    const int fq = lane >> 4;            // k-chunk selector (0..3)

    const size_t rbA = (size_t)Kd * 2;   // row stride in bytes (A and BT)
    const char* Ag = (const char*)A  + (size_t)bm * rbA;
    const char* Bg = (const char*)BT + (size_t)bn * rbA;

    f32x4 acc[8][4];
#pragma unroll
    for (int i = 0; i < 8; i++)
#pragma unroll
        for (int j = 0; j < 4; j++) acc[i][j] = (f32x4){0.f, 0.f, 0.f, 0.f};

    // ---- stage tile t into ring[t&1]: per thread 2 rounds x (A,B) = 4 loads.
    // LDS dest is linear (wave-uniform base + lane*16 implicit); the global
    // SOURCE is slot-swizzled so that swizzled ds_reads see linear data.
    auto STAGE = [&](int t) {
        char* dA = smem + (size_t)(t & 1) * 32768;
        char* dB = dA + 16384;
        const size_t kb = (size_t)t * 64;     // 32 bf16 = 64 bytes per K-step
#pragma unroll
        for (int r = 0; r < 2; ++r) {
            const int o   = r * 8192 + tid * 16;
            const int row = o >> 6;
            const int sw  = (((o >> 4) & 3) ^ ((row >> 1) & 3)) << 4;
            __builtin_amdgcn_global_load_lds(
                (const __attribute__((address_space(1))) void*)(Ag + (size_t)row * rbA + kb + sw),
                (__attribute__((address_space(3))) void*)(dA + r * 8192 + wid * 1024),
                16, 0, 0);
            __builtin_amdgcn_global_load_lds(
                (const __attribute__((address_space(1))) void*)(Bg + (size_t)row * rbA + kb + sw),
                (__attribute__((address_space(3))) void*)(dB + r * 8192 + wid * 1024),
                16, 0, 0);
        }
    };

    // ---- compute tile t from ring[t&1]: software-pipelined quadrants.
    auto COMPUTE = [&](int t) {
        const char* As_ = smem + (size_t)(t & 1) * 32768;
        const char* Bs_ = As_ + 16384;
        auto lda = [&](int mi) -> bf16x8 {
            const int row = wrow + mi * 16 + fr;
            return *(const bf16x8*)(As_ + row * 64 + ((fq ^ ((row >> 1) & 3)) << 4));
        };
        bf16x8 b_[4];
#pragma unroll
        for (int ni = 0; ni < 4; ++ni) {
            const int row = wcol + ni * 16 + fr;
            b_[ni] = *(const bf16x8*)(Bs_ + row * 64 + ((fq ^ ((row >> 1) & 3)) << 4));
        }
        bf16x8 a0 = lda(0), a1 = lda(1);
        __builtin_amdgcn_s_setprio(1);
#pragma unroll
        for (int q = 0; q < 4; ++q) {
            bf16x8 n0, n1;
            if (q < 3) { n0 = lda(2 * q + 2); n1 = lda(2 * q + 3); }
#pragma unroll
            for (int ni = 0; ni < 4; ++ni)
                acc[2 * q][ni] = __builtin_amdgcn_mfma_f32_16x16x32_bf16(
                    a0, b_[ni], acc[2 * q][ni], 0, 0, 0);
#pragma unroll
            for (int ni = 0; ni < 4; ++ni)
                acc[2 * q + 1][ni] = __builtin_amdgcn_mfma_f32_16x16x32_bf16(
                    a1, b_[ni], acc[2 * q + 1][ni], 0, 0, 0);
            a0 = n0; a1 = n1;
        }
        __builtin_amdgcn_s_setprio(0);
    };

    // ---- prologue: land tile 0
    STAGE(0);
    vm_drain();
    __builtin_amdgcn_s_barrier();

    // ---- main loop: stage t+1 (lands during compute t), compute t, drain,
    // barrier. Slot (t+1)&1 was last read in COMPUTE(t-1), whose reads
    // completed before the previous barrier -> write-after-read safe.
    int t = 0;
    for (; t < NT - 1; ++t) {
        STAGE(t + 1);
        COMPUTE(t);
        vm_drain();
        __builtin_amdgcn_s_barrier();
    }
    COMPUTE(NT - 1);

    // ---- epilogue. Opaque the bias pointer so LICM can't hoist its loads
    // into the K-loop.
    const float* bias_o = bias;
    asm volatile("" : "+s"(bias_o));
#pragma unroll
    for (int mi = 0; mi < 8; ++mi) {
#pragma unroll
        for (int ni = 0; ni < 4; ++ni) {
            const int c = bn + wcol + ni * 16 + fr;
            const float bv = bias_o[c];
#pragma unroll
            for (int rg = 0; rg < 4; ++rg) {
                const int r = bm + wrow + mi * 16 + fq * 4 + rg;
                float v = acc[mi][ni][rg] + bv;
                if (RELU) v = fmaxf(v, 0.f);
                if constexpr (std::is_same_v<TC, float>)
                    Cout[(size_t)r * Nld + c] = v;
                else
                    Cout[(size_t)r * Nld + c] = f2b(v);
            }
        }
    }
}

// ---------------------------------------------------------------------------
// Split x (fp32) -> A' bf16 [NTOK][3072] = [x_hi | x_lo | x_hi]
// ---------------------------------------------------------------------------
__global__ __launch_bounds__(256) void split_x(
    const float* __restrict__ x, unsigned short* __restrict__ A2)
{
    const int n = blockIdx.x;
    const int c = threadIdx.x * 4;
    const float4 v = *(const float4*)(x + (size_t)n * C_ + c);
    ushort4 hi, lo;
    hi.x = f2b(v.x); lo.x = f2b(v.x - b2f(hi.x));
    hi.y = f2b(v.y); lo.y = f2b(v.y - b2f(hi.y));
    hi.z = f2b(v.z); lo.z = f2b(v.z - b2f(hi.z));
    hi.w = f2b(v.w); lo.w = f2b(v.w - b2f(hi.w));
    unsigned short* row = A2 + (size_t)n * KR_;
    *(ushort4*)(row + c)            = hi;
    *(ushort4*)(row + C_ + c)       = lo;
    *(ushort4*)(row + 2 * C_ + c)   = hi;
}

// ---------------------------------------------------------------------------
// Split+transpose rw1 [C][H] fp32 -> B'^T bf16 [H][3072] = [w_hi | w_hi | w_lo]
// ---------------------------------------------------------------------------
__global__ __launch_bounds__(256) void split_w(
    const float* __restrict__ in, unsigned short* __restrict__ out)
{
    __shared__ float t[32][33];
    const int rb = blockIdx.y * 32;   // c-dim tile
    const int cb = blockIdx.x * 32;   // h-dim tile
    const int tr = threadIdx.x >> 3, tc = (threadIdx.x & 7) * 4;
    const float4 v = *(const float4*)(in + (size_t)(rb + tr) * H_ + cb + tc);
    t[tr][tc + 0] = v.x; t[tr][tc + 1] = v.y; t[tr][tc + 2] = v.z; t[tr][tc + 3] = v.w;
    __syncthreads();
    ushort4 hi, lo;
    float f;
    f = t[tc + 0][tr]; hi.x = f2b(f); lo.x = f2b(f - b2f(hi.x));
    f = t[tc + 1][tr]; hi.y = f2b(f); lo.y = f2b(f - b2f(hi.y));
    f = t[tc + 2][tr]; hi.z = f2b(f); lo.z = f2b(f - b2f(hi.z));
    f = t[tc + 3][tr]; hi.w = f2b(f); lo.w = f2b(f - b2f(hi.w));
    unsigned short* row = out + (size_t)(cb + tr) * KR_;
    *(ushort4*)(row + rb + tc)           = hi;
    *(ushort4*)(row + C_ + rb + tc)      = hi;
    *(ushort4*)(row + 2 * C_ + rb + tc)  = lo;
}

// ---------------------------------------------------------------------------
// Tiled transpose + fp32->bf16 convert: in [z][R][Ncols] f32 -> out [z][Ncols][R] bf16
// ---------------------------------------------------------------------------
__global__ __launch_bounds__(256) void transpose_cvt(
    const float* __restrict__ in, unsigned short* __restrict__ out, int R, int Ncols)
{
    __shared__ float t[32][33];
    const size_t zoff = (size_t)blockIdx.z * R * Ncols;
    in  += zoff;
    out += zoff;
    const int rb = blockIdx.y * 32, cb = blockIdx.x * 32;
    const int tr = threadIdx.x >> 3, tc = (threadIdx.x & 7) * 4;
    const float4 v = *(const float4*)(in + (size_t)(rb + tr) * Ncols + cb + tc);
    t[tr][tc + 0] = v.x; t[tr][tc + 1] = v.y; t[tr][tc + 2] = v.z; t[tr][tc + 3] = v.w;
    __syncthreads();
    ushort4 u;
    u.x = f2b(t[tc + 0][tr]); u.y = f2b(t[tc + 1][tr]);
    u.z = f2b(t[tc + 2][tr]); u.w = f2b(t[tc + 3][tr]);
    *(ushort4*)(out + (size_t)(cb + tr) * R + rb + tc) = u;
}

// ---------------------------------------------------------------------------
// Router second GEMM (H x 8) + top-2 + softmax, fused. One block per token.
// ---------------------------------------------------------------------------
__global__ __launch_bounds__(256) void router_topk(
    const float* __restrict__ h1, const float* __restrict__ rw2,
    const float* __restrict__ rb2, int* __restrict__ ids, float* __restrict__ probs)
{
    const int n = blockIdx.x;
    const float* hrow = h1 + (size_t)n * H_;
    float acc[E_];
#pragma unroll
    for (int e = 0; e < E_; e++) acc[e] = 0.f;
    for (int h = threadIdx.x; h < H_; h += 256) {
        const float hv = hrow[h];
        const float4 w0 = *(const float4*)(rw2 + (size_t)h * E_);
        const float4 w1 = *(const float4*)(rw2 + (size_t)h * E_ + 4);
        acc[0] = fmaf(hv, w0.x, acc[0]); acc[1] = fmaf(hv, w0.y, acc[1]);
        acc[2] = fmaf(hv, w0.z, acc[2]); acc[3] = fmaf(hv, w0.w, acc[3]);
        acc[4] = fmaf(hv, w1.x, acc[4]); acc[5] = fmaf(hv, w1.y, acc[5]);
        acc[6] = fmaf(hv, w1.z, acc[6]); acc[7] = fmaf(hv, w1.w, acc[7]);
    }
    __shared__ float red[E_][256];
#pragma unroll
    for (int e = 0; e < E_; e++) red[e][threadIdx.x] = acc[e];
    __syncthreads();
    for (int st = 128; st > 0; st >>= 1) {
        if (threadIdx.x < st) {
#pragma unroll
            for (int e = 0; e < E_; e++) red[e][threadIdx.x] += red[e][threadIdx.x + st];
        }
        __syncthreads();
    }
    if (threadIdx.x == 0) {
        float v1 = -1e30f, v2 = -1e30f; int i1 = 0, i2 = 0;
#pragma unroll
        for (int e = 0; e < E_; e++) {
            const float v = red[e][0] + rb2[e];
            if (v > v1)      { v2 = v1; i2 = i1; v1 = v; i1 = e; }
            else if (v > v2) { v2 = v;  i2 = e; }
        }
        const float e2 = expf(v2 - v1);
        const float inv = 1.f / (1.f + e2);
        ids[n * 2] = i1;  ids[n * 2 + 1] = i2;
        probs[n * 2] = inv; probs[n * 2 + 1] = e2 * inv;
    }
}

// ---------------------------------------------------------------------------
// Exact sequential per-expert prefix count (reference cumsum semantics).
// ---------------------------------------------------------------------------
__global__ __launch_bounds__(256) void compute_pos(
    const int* __restrict__ ids, int* __restrict__ pos)
{
    __shared__ int hist[256][E_];
    const int t = threadIdx.x;
    const int per = NSLOT / 256;   // 128
    int cnt[E_];
#pragma unroll
    for (int e = 0; e < E_; e++) cnt[e] = 0;
    const int s0 = t * per;
    for (int i = 0; i < per; i++) cnt[ids[s0 + i]]++;
#pragma unroll
    for (int e = 0; e < E_; e++) hist[t][e] = cnt[e];
    __syncthreads();
    if (t < E_) {
        int run = 0;
        for (int i = 0; i < 256; i++) { const int c = hist[i][t]; hist[i][t] = run; run += c; }
    }
    __syncthreads();
    int run[E_];
#pragma unroll
    for (int e = 0; e < E_; e++) run[e] = hist[t][e];
    for (int i = 0; i < per; i++) { const int e = ids[s0 + i]; pos[s0 + i] = run[e]++; }
}

// ---------------------------------------------------------------------------
// Dispatch: copy kept tokens into per-expert buffers (bf16).
// ---------------------------------------------------------------------------
__global__ __launch_bounds__(256) void dispatch_k(
    const float* __restrict__ x, const int* __restrict__ ids,
    const int* __restrict__ pos, unsigned short* __restrict__ disp)
{
    const int s = blockIdx.x;
    const int e = ids[s], p = pos[s];
    if (p >= CAP_) return;                      // dropped over capacity
    const int n = s >> 1;                       // K_ == 2
    const float4 v = *(const float4*)(x + (size_t)n * C_ + threadIdx.x * 4);
    ushort4 u;
    u.x = f2b(v.x); u.y = f2b(v.y); u.z = f2b(v.z); u.w = f2b(v.w);
    *(ushort4*)(disp + ((size_t)e * CAP_ + p) * C_ + threadIdx.x * 4) = u;
}

// ---------------------------------------------------------------------------
// Combine (gather, race-free): y[n] = sum_k probs * eo[id_k, pos_k]
// ---------------------------------------------------------------------------
__global__ __launch_bounds__(256) void combine_k(
    const unsigned short* __restrict__ eo, const int* __restrict__ ids,
    const int* __restrict__ pos, const float* __restrict__ probs,
    float* __restrict__ y)
{
    const int n = blockIdx.x;
    const int c = threadIdx.x * 4;
    float r0 = 0.f, r1 = 0.f, r2 = 0.f, r3 = 0.f;
#pragma unroll
    for (int k = 0; k < K_; k++) {
        const int p = pos[2 * n + k];
        if (p >= CAP_) continue;
        const int e = ids[2 * n + k];
        const float w = probs[2 * n + k];
        const ushort4 u = *(const ushort4*)(eo + ((size_t)e * CAP_ + p) * C_ + c);
        r0 = fmaf(w, b2f(u.x), r0); r1 = fmaf(w, b2f(u.y), r1);
        r2 = fmaf(w, b2f(u.z), r2); r3 = fmaf(w, b2f(u.w), r3);
    }
    *(float4*)(y + (size_t)n * C_ + c) = make_float4(r0, r1, r2, r3);
}

// ---------------------------------------------------------------------------
extern "C" void kernel_launch(void* const* d_in, const int* in_sizes, int n_in,
                              void* d_out, int out_size, void* d_ws, size_t ws_size,
                              hipStream_t stream)
{
    const float* x   = (const float*)d_in[0];
    const float* rw1 = (const float*)d_in[1];
    const float* rb1 = (const float*)d_in[2];
    const float* rw2 = (const float*)d_in[3];
    const float* rb2 = (const float*)d_in[4];
    const float* ew1 = (const float*)d_in[5];
    const float* eb1 = (const float*)d_in[6];
    const float* ew2 = (const float*)d_in[7];
    const float* eb2 = (const float*)d_in[8];
    float* y = (float*)d_out;

    // ws layout (403 MB + meta), aliased by liveness:
    //   [0,256MiB)       h1 f32 [16384][4096]  -> later hexp bf16 [8][4096][4096]
    //   [256MiB,352MiB)  A' bf16 [16384][3072] (router) -> later disp/eo bf16 (64MiB)
    //   [352MiB,376MiB)  B' bf16 [4096][3072]  (router)
    //   [320MiB,384MiB)  BTW bf16 (expert weights, written AFTER router GEMM)
    //   [384MiB,...)     ids / probs / pos (128KB each)
    char* ws = (char*)d_ws;
    float*          h1    = (float*)ws;
    unsigned short* hexp  = (unsigned short*)ws;
    unsigned short* A2    = (unsigned short*)(ws + 268435456L);   // 96 MiB
    unsigned short* B2    = (unsigned short*)(ws + 369098752L);   // 24 MiB
    unsigned short* disp  = (unsigned short*)(ws + 268435456L);
    unsigned short* eo    = (unsigned short*)(ws + 268435456L);
    unsigned short* BTW   = (unsigned short*)(ws + 335544320L);
    int*            ids   = (int*)  (ws + 402653184L);
    float*          probs = (float*)(ws + 402784256L);
    int*            pos   = (int*)  (ws + 402915328L);

    const size_t LDSB = 65536;   // 64 KiB ring-2 -> 2 blocks/CU

    // 1a) Build split operands for router GEMM1
    split_x<<<NTOK, 256, 0, stream>>>(x, A2);
    {
        dim3 g(H_ / 32, C_ / 32, 1);
        split_w<<<g, 256, 0, stream>>>(rw1, B2);
    }
    // 1b) Router GEMM1 on MFMA (split-bf16, ~fp32 exact):
    //     h1 = relu([x_hi|x_lo|x_hi] @ [w_hi;w_hi;w_lo] + rb1), fp32 out
    {
        dim3 g(H_ / 256, NTOK / 256, 1);   // 16 x 64
        gemm256_pipe<1, float><<<g, 512, LDSB, stream>>>(
            A2, B2, rb1, h1, KR_, H_, KR_ / 32, 0, 0, 0, 0);
    }
    // 2) Router GEMM2 + top-2 + softmax
    router_topk<<<NTOK, 256, 0, stream>>>(h1, rw2, rb2, ids, probs);
    // 3) Exact sequential capacity positions
    compute_pos<<<1, 256, 0, stream>>>(ids, pos);
    // 4) Dispatch tokens to expert buffers (bf16) — overwrites A' region (dead)
    dispatch_k<<<NSLOT, 256, 0, stream>>>(x, ids, pos, disp);
    // 5a) Convert+transpose ew1 [8][1024][4096] -> BT1 bf16 [8][4096][1024]
    {
        dim3 g(H_ / 32, C_ / 32, E_);
        transpose_cvt<<<g, 256, 0, stream>>>(ew1, BTW, C_, H_);
    }
    // 5b) Expert GEMM1 (MFMA): hexp = relu(disp @ ew1 + eb1)
    {
        dim3 g(H_ / 256, CAP_ / 256, E_);   // 16 x 16 x 8
        gemm256_pipe<1, unsigned short><<<g, 512, LDSB, stream>>>(
            disp, BTW, eb1, hexp, C_, H_, C_ / 32,
            (long)CAP_ * C_, (long)H_ * C_, (long)H_, (long)CAP_ * H_);
    }
    // 6a) Convert+transpose ew2 [8][4096][1024] -> BT2 bf16 [8][1024][4096]
    {
        dim3 g(C_ / 32, H_ / 32, E_);
        transpose_cvt<<<g, 256, 0, stream>>>(ew2, BTW, H_, C_);
    }
    // 6b) Expert GEMM2 (MFMA): eo = hexp @ ew2 + eb2   (bf16 out, gathered later)
    {
        dim3 g(C_ / 256, CAP_ / 256, E_);   // 4 x 16 x 8
        gemm256_pipe<0, unsigned short><<<g, 512, LDSB, stream>>>(
            hexp, BTW, eb2, eo, H_, C_, H_ / 32,
            (long)CAP_ * H_, (long)C_ * H_, (long)C_, (long)CAP_ * C_);
    }
    // 7) Combine: gather expert outputs, weight, sum (race-free, writes all of y)
    combine_k<<<NTOK, 256, 0, stream>>>(eo, ids, pos, probs, y);
}

// Round 8
// 1289.117 us; speedup vs baseline: 6.1861x; 6.1861x over previous
//
#include <hip/hip_runtime.h>
#include <cstdint>
#include <type_traits>

#define B_    8
#define T_    2048
#define C_    1024
#define E_    8
#define K_    2
#define CAP_  4096
#define H_    4096
#define NTOK  (B_ * T_)      // 16384
#define NSLOT (NTOK * K_)    // 32768
#define KR_   3072           // router split-GEMM K: [x_hi | x_lo | x_hi]

typedef __bf16 bf16x8 __attribute__((ext_vector_type(8)));
typedef float  f32x4  __attribute__((ext_vector_type(4)));
typedef float  f32x16 __attribute__((ext_vector_type(16)));

static __device__ __forceinline__ float b2f(unsigned short u) {
    union { float f; unsigned int i; } v; v.i = ((unsigned int)u) << 16; return v.f;
}
static __device__ __forceinline__ unsigned short f2b(float f) {
    unsigned int x = __float_as_uint(f);
    unsigned int r = (x + 0x7fffu + ((x >> 16) & 1u)) >> 16;   // RNE
    return (unsigned short)r;
}

template<int W> static __device__ __forceinline__ void vm_wait() {
    if constexpr (W == 8) asm volatile("s_waitcnt vmcnt(8)" ::: "memory");
    else if constexpr (W == 4) asm volatile("s_waitcnt vmcnt(4)" ::: "memory");
    else if constexpr (W == 0) asm volatile("s_waitcnt vmcnt(0)" ::: "memory");
}

// ---------------------------------------------------------------------------
// Deep-pipelined MFMA bf16 GEMM: 256x256 tile, BK=32, 512 threads (8 waves,
// 2Mx4N, wave tile 128x64), ring-4 LDS K-tile buffers (128 KiB dynamic),
// 3-tile prefetch with counted vmcnt(8) (never 0 in main loop), XOR
// bank-swizzle on LDS (both-sides: pre-swizzled global_load_lds source +
// swizzled ds_read). Inner loop: v_mfma_f32_32x32x16_bf16 (rate-optimal
// shape, 16 MFMA + 12 ds_read_b128 per K-iter per wave), software-pipelined
// A-fragment prefetch under the MFMA burst. One barrier per K-iter.
// NOTE: register demand ~250/wave (124 arch + 128 acc) -> 2 waves/SIMD ->
// 1 block/CU is structural for this tile; do NOT raise launch_bounds min
// waves (round-7 spill disaster: budget 128 -> acc spilled to scratch).
// A [M][Kd] bf16 row-major, BT [N][Kd] bf16 (pre-transposed). Out [M][Nld].
// Requires M%256==0, N%256==0, Kd%32==0, NT=Kd/32 >= 4, grid.x*grid.y%8==0.
// ---------------------------------------------------------------------------
template<int RELU, typename TC>
__global__ __launch_bounds__(512, 2) void gemm256_pipe(
    const unsigned short* __restrict__ A, const unsigned short* __restrict__ BT,
    const float* __restrict__ bias, TC* __restrict__ Cout,
    int Kd, int Nld, int NT,
    long sA, long sB, long sBias, long sC)
{
    extern __shared__ char smem[];   // 4 ring slots x (A 16KB | B 16KB)

    const int z = blockIdx.z;
    A    += (size_t)z * sA;
    BT   += (size_t)z * sB;
    bias += (size_t)z * sBias;
    Cout += (size_t)z * sC;

    // XCD-aware swizzle (nwg % 8 == 0 for all our grids)
    const int gx = gridDim.x;
    const int nwg = gx * gridDim.y;
    int wg = blockIdx.y * gx + blockIdx.x;
    wg = (wg & 7) * (nwg >> 3) + (wg >> 3);
    const int bm = (wg / gx) * 256;
    const int bn = (wg % gx) * 256;

    const int tid  = threadIdx.x;
    const int lane = tid & 63;
    const int wid  = tid >> 6;
    const int wrow = (wid >> 2) * 128;   // wave M offset (2 waves in M)
    const int wcol = (wid & 3) * 64;     // wave N offset (4 waves in N)
    const int lr = lane & 31;            // row within 32-block
    const int kh = lane >> 5;            // k-half selector (0..1)

    const size_t rbA = (size_t)Kd * 2;   // row stride in bytes (A and BT)
    const char* Ag = (const char*)A  + (size_t)bm * rbA;
    const char* Bg = (const char*)BT + (size_t)bn * rbA;

    f32x16 acc[4][2];                    // [rowblock 32][colblock 32]
#pragma unroll
    for (int i = 0; i < 4; i++)
#pragma unroll
        for (int j = 0; j < 2; j++)
#pragma unroll
            for (int r = 0; r < 16; r++) acc[i][j][r] = 0.f;

    // ---- stage tile t into ring[t&3]: per thread 2 rounds x (A,B) = 4 loads.
    // LDS dest is linear (wave-uniform base + lane*16 implicit); the global
    // SOURCE is slot-swizzled so that swizzled ds_reads see linear data.
    auto STAGE = [&](int t) {
        char* dA = smem + (size_t)(t & 3) * 32768;
        char* dB = dA + 16384;
        const size_t kb = (size_t)t * 64;     // 32 bf16 = 64 bytes per K-step
#pragma unroll
        for (int r = 0; r < 2; ++r) {
            const int o   = r * 8192 + tid * 16;
            const int row = o >> 6;
            const int sw  = (((o >> 4) & 3) ^ ((row >> 1) & 3)) << 4;
            __builtin_amdgcn_global_load_lds(
                (const __attribute__((address_space(1))) void*)(Ag + (size_t)row * rbA + kb + sw),
                (__attribute__((address_space(3))) void*)(dA + r * 8192 + wid * 1024),
                16, 0, 0);
            __builtin_amdgcn_global_load_lds(
                (const __attribute__((address_space(1))) void*)(Bg + (size_t)row * rbA + kb + sw),
                (__attribute__((address_space(3))) void*)(dB + r * 8192 + wid * 1024),
                16, 0, 0);
        }
    };

    // ---- compute tile t from ring[t&3]: 12 swizzled ds_read_b128 +
    // 16 x mfma_32x32x16, A-pair prefetched under the MFMA burst.
    auto COMPUTE = [&](int t) {
        const char* As_ = smem + (size_t)(t & 3) * 32768;
        const char* Bs_ = As_ + 16384;
        auto lda = [&](int ri, int ks) -> bf16x8 {
            const int row = wrow + ri * 32 + lr;
            const int slot = ((ks << 1) + kh) ^ ((row >> 1) & 3);
            return *(const bf16x8*)(As_ + row * 64 + slot * 16);
        };
        auto ldb = [&](int ci, int ks) -> bf16x8 {
            const int row = wcol + ci * 32 + lr;
            const int slot = ((ks << 1) + kh) ^ ((row >> 1) & 3);
            return *(const bf16x8*)(Bs_ + row * 64 + slot * 16);
        };
        bf16x8 b00 = ldb(0, 0), b01 = ldb(0, 1);
        bf16x8 b10 = ldb(1, 0), b11 = ldb(1, 1);
        bf16x8 a0 = lda(0, 0), a1 = lda(0, 1);
        __builtin_amdgcn_s_setprio(1);
#pragma unroll
        for (int ri = 0; ri < 4; ++ri) {
            bf16x8 n0, n1;
            if (ri < 3) { n0 = lda(ri + 1, 0); n1 = lda(ri + 1, 1); }
            acc[ri][0] = __builtin_amdgcn_mfma_f32_32x32x16_bf16(a0, b00, acc[ri][0], 0, 0, 0);
            acc[ri][1] = __builtin_amdgcn_mfma_f32_32x32x16_bf16(a0, b10, acc[ri][1], 0, 0, 0);
            acc[ri][0] = __builtin_amdgcn_mfma_f32_32x32x16_bf16(a1, b01, acc[ri][0], 0, 0, 0);
            acc[ri][1] = __builtin_amdgcn_mfma_f32_32x32x16_bf16(a1, b11, acc[ri][1], 0, 0, 0);
            a0 = n0; a1 = n1;
        }
        __builtin_amdgcn_s_setprio(0);
    };

    // ---- prologue: 3 tiles in flight; tile 0 landed after vmcnt(8)
    STAGE(0); STAGE(1); STAGE(2);
    vm_wait<8>();
    __builtin_amdgcn_s_barrier();

    // ---- main loop: stage t+3, compute t, wait tile t+1 (8 loads outstanding)
    int t = 0;
    for (; t < NT - 3; ++t) {
        STAGE(t + 3);
        COMPUTE(t);
        vm_wait<8>();
        __builtin_amdgcn_s_barrier();
    }
    // ---- peeled tail (no more stages; counted waits shrink 4 -> 0)
    COMPUTE(NT - 3);
    vm_wait<4>();
    __builtin_amdgcn_s_barrier();
    COMPUTE(NT - 2);
    vm_wait<0>();
    __builtin_amdgcn_s_barrier();
    COMPUTE(NT - 1);

    // ---- epilogue. C/D layout (32x32, m74/m101): col = lane&31,
    // row = (reg&3) + 8*(reg>>2) + 4*(lane>>5). Opaque bias ptr vs LICM.
    const float* bias_o = bias;
    asm volatile("" : "+s"(bias_o));
#pragma unroll
    for (int ri = 0; ri < 4; ++ri) {
#pragma unroll
        for (int ci = 0; ci < 2; ++ci) {
            const int c = bn + wcol + ci * 32 + lr;
            const float bv = bias_o[c];
#pragma unroll
            for (int rg = 0; rg < 16; ++rg) {
                const int r = bm + wrow + ri * 32 + (rg & 3) + 8 * (rg >> 2) + 4 * kh;
                float v = acc[ri][ci][rg] + bv;
                if (RELU) v = fmaxf(v, 0.f);
                if constexpr (std::is_same_v<TC, float>)
                    Cout[(size_t)r * Nld + c] = v;
                else
                    Cout[(size_t)r * Nld + c] = f2b(v);
            }
        }
    }
}

// ---------------------------------------------------------------------------
// Split x (fp32) -> A' bf16 [NTOK][3072] = [x_hi | x_lo | x_hi]
// ---------------------------------------------------------------------------
__global__ __launch_bounds__(256) void split_x(
    const float* __restrict__ x, unsigned short* __restrict__ A2)
{
    const int n = blockIdx.x;
    const int c = threadIdx.x * 4;
    const float4 v = *(const float4*)(x + (size_t)n * C_ + c);
    ushort4 hi, lo;
    hi.x = f2b(v.x); lo.x = f2b(v.x - b2f(hi.x));
    hi.y = f2b(v.y); lo.y = f2b(v.y - b2f(hi.y));
    hi.z = f2b(v.z); lo.z = f2b(v.z - b2f(hi.z));
    hi.w = f2b(v.w); lo.w = f2b(v.w - b2f(hi.w));
    unsigned short* row = A2 + (size_t)n * KR_;
    *(ushort4*)(row + c)            = hi;
    *(ushort4*)(row + C_ + c)       = lo;
    *(ushort4*)(row + 2 * C_ + c)   = hi;
}

// ---------------------------------------------------------------------------
// Split+transpose rw1 [C][H] fp32 -> B'^T bf16 [H][3072] = [w_hi | w_hi | w_lo]
// ---------------------------------------------------------------------------
__global__ __launch_bounds__(256) void split_w(
    const float* __restrict__ in, unsigned short* __restrict__ out)
{
    __shared__ float t[32][33];
    const int rb = blockIdx.y * 32;   // c-dim tile
    const int cb = blockIdx.x * 32;   // h-dim tile
    const int tr = threadIdx.x >> 3, tc = (threadIdx.x & 7) * 4;
    const float4 v = *(const float4*)(in + (size_t)(rb + tr) * H_ + cb + tc);
    t[tr][tc + 0] = v.x; t[tr][tc + 1] = v.y; t[tr][tc + 2] = v.z; t[tr][tc + 3] = v.w;
    __syncthreads();
    ushort4 hi, lo;
    float f;
    f = t[tc + 0][tr]; hi.x = f2b(f); lo.x = f2b(f - b2f(hi.x));
    f = t[tc + 1][tr]; hi.y = f2b(f); lo.y = f2b(f - b2f(hi.y));
    f = t[tc + 2][tr]; hi.z = f2b(f); lo.z = f2b(f - b2f(hi.z));
    f = t[tc + 3][tr]; hi.w = f2b(f); lo.w = f2b(f - b2f(hi.w));
    unsigned short* row = out + (size_t)(cb + tr) * KR_;
    *(ushort4*)(row + rb + tc)           = hi;
    *(ushort4*)(row + C_ + rb + tc)      = hi;
    *(ushort4*)(row + 2 * C_ + rb + tc)  = lo;
}

// ---------------------------------------------------------------------------
// Tiled transpose + fp32->bf16 convert: in [z][R][Ncols] f32 -> out [z][Ncols][R] bf16
// ---------------------------------------------------------------------------
__global__ __launch_bounds__(256) void transpose_cvt(
    const float* __restrict__ in, unsigned short* __restrict__ out, int R, int Ncols)
{
    __shared__ float t[32][33];
    const size_t zoff = (size_t)blockIdx.z * R * Ncols;
    in  += zoff;
    out += zoff;
    const int rb = blockIdx.y * 32, cb = blockIdx.x * 32;
    const int tr = threadIdx.x >> 3, tc = (threadIdx.x & 7) * 4;
    const float4 v = *(const float4*)(in + (size_t)(rb + tr) * Ncols + cb + tc);
    t[tr][tc + 0] = v.x; t[tr][tc + 1] = v.y; t[tr][tc + 2] = v.z; t[tr][tc + 3] = v.w;
    __syncthreads();
    ushort4 u;
    u.x = f2b(t[tc + 0][tr]); u.y = f2b(t[tc + 1][tr]);
    u.z = f2b(t[tc + 2][tr]); u.w = f2b(t[tc + 3][tr]);
    *(ushort4*)(out + (size_t)(cb + tr) * R + rb + tc) = u;
}

// ---------------------------------------------------------------------------
// Router second GEMM (H x 8) + top-2 + softmax, fused. One block per token.
// ---------------------------------------------------------------------------
__global__ __launch_bounds__(256) void router_topk(
    const float* __restrict__ h1, const float* __restrict__ rw2,
    const float* __restrict__ rb2, int* __restrict__ ids, float* __restrict__ probs)
{
    const int n = blockIdx.x;
    const float* hrow = h1 + (size_t)n * H_;
    float acc[E_];
#pragma unroll
    for (int e = 0; e < E_; e++) acc[e] = 0.f;
    for (int h = threadIdx.x; h < H_; h += 256) {
        const float hv = hrow[h];
        const float4 w0 = *(const float4*)(rw2 + (size_t)h * E_);
        const float4 w1 = *(const float4*)(rw2 + (size_t)h * E_ + 4);
        acc[0] = fmaf(hv, w0.x, acc[0]); acc[1] = fmaf(hv, w0.y, acc[1]);
        acc[2] = fmaf(hv, w0.z, acc[2]); acc[3] = fmaf(hv, w0.w, acc[3]);
        acc[4] = fmaf(hv, w1.x, acc[4]); acc[5] = fmaf(hv, w1.y, acc[5]);
        acc[6] = fmaf(hv, w1.z, acc[6]); acc[7] = fmaf(hv, w1.w, acc[7]);
    }
    __shared__ float red[E_][256];
#pragma unroll
    for (int e = 0; e < E_; e++) red[e][threadIdx.x] = acc[e];
    __syncthreads();
    for (int st = 128; st > 0; st >>= 1) {
        if (threadIdx.x < st) {
#pragma unroll
            for (int e = 0; e < E_; e++) red[e][threadIdx.x] += red[e][threadIdx.x + st];
        }
        __syncthreads();
    }
    if (threadIdx.x == 0) {
        float v1 = -1e30f, v2 = -1e30f; int i1 = 0, i2 = 0;
#pragma unroll
        for (int e = 0; e < E_; e++) {
            const float v = red[e][0] + rb2[e];
            if (v > v1)      { v2 = v1; i2 = i1; v1 = v; i1 = e; }
            else if (v > v2) { v2 = v;  i2 = e; }
        }
        const float e2 = expf(v2 - v1);
        const float inv = 1.f / (1.f + e2);
        ids[n * 2] = i1;  ids[n * 2 + 1] = i2;
        probs[n * 2] = inv; probs[n * 2 + 1] = e2 * inv;
    }
}

// ---------------------------------------------------------------------------
// Exact sequential per-expert prefix count (reference cumsum semantics).
// ---------------------------------------------------------------------------
__global__ __launch_bounds__(256) void compute_pos(
    const int* __restrict__ ids, int* __restrict__ pos)
{
    __shared__ int hist[256][E_];
    const int t = threadIdx.x;
    const int per = NSLOT / 256;   // 128
    int cnt[E_];
#pragma unroll
    for (int e = 0; e < E_; e++) cnt[e] = 0;
    const int s0 = t * per;
    for (int i = 0; i < per; i++) cnt[ids[s0 + i]]++;
#pragma unroll
    for (int e = 0; e < E_; e++) hist[t][e] = cnt[e];
    __syncthreads();
    if (t < E_) {
        int run = 0;
        for (int i = 0; i < 256; i++) { const int c = hist[i][t]; hist[i][t] = run; run += c; }
    }
    __syncthreads();
    int run[E_];
#pragma unroll
    for (int e = 0; e < E_; e++) run[e] = hist[t][e];
    for (int i = 0; i < per; i++) { const int e = ids[s0 + i]; pos[s0 + i] = run[e]++; }
}

// ---------------------------------------------------------------------------
// Dispatch: copy kept tokens into per-expert buffers (bf16).
// ---------------------------------------------------------------------------
__global__ __launch_bounds__(256) void dispatch_k(
    const float* __restrict__ x, const int* __restrict__ ids,
    const int* __restrict__ pos, unsigned short* __restrict__ disp)
{
    const int s = blockIdx.x;
    const int e = ids[s], p = pos[s];
    if (p >= CAP_) return;                      // dropped over capacity
    const int n = s >> 1;                       // K_ == 2
    const float4 v = *(const float4*)(x + (size_t)n * C_ + threadIdx.x * 4);
    ushort4 u;
    u.x = f2b(v.x); u.y = f2b(v.y); u.z = f2b(v.z); u.w = f2b(v.w);
    *(ushort4*)(disp + ((size_t)e * CAP_ + p) * C_ + threadIdx.x * 4) = u;
}

// ---------------------------------------------------------------------------
// Combine (gather, race-free): y[n] = sum_k probs * eo[id_k, pos_k]
// ---------------------------------------------------------------------------
__global__ __launch_bounds__(256) void combine_k(
    const unsigned short* __restrict__ eo, const int* __restrict__ ids,
    const int* __restrict__ pos, const float* __restrict__ probs,
    float* __restrict__ y)
{
    const int n = blockIdx.x;
    const int c = threadIdx.x * 4;
    float r0 = 0.f, r1 = 0.f, r2 = 0.f, r3 = 0.f;
#pragma unroll
    for (int k = 0; k < K_; k++) {
        const int p = pos[2 * n + k];
        if (p >= CAP_) continue;
        const int e = ids[2 * n + k];
        const float w = probs[2 * n + k];
        const ushort4 u = *(const ushort4*)(eo + ((size_t)e * CAP_ + p) * C_ + c);
        r0 = fmaf(w, b2f(u.x), r0); r1 = fmaf(w, b2f(u.y), r1);
        r2 = fmaf(w, b2f(u.z), r2); r3 = fmaf(w, b2f(u.w), r3);
    }
    *(float4*)(y + (size_t)n * C_ + c) = make_float4(r0, r1, r2, r3);
}

// ---------------------------------------------------------------------------
extern "C" void kernel_launch(void* const* d_in, const int* in_sizes, int n_in,
                              void* d_out, int out_size, void* d_ws, size_t ws_size,
                              hipStream_t stream)
{
    const float* x   = (const float*)d_in[0];
    const float* rw1 = (const float*)d_in[1];
    const float* rb1 = (const float*)d_in[2];
    const float* rw2 = (const float*)d_in[3];
    const float* rb2 = (const float*)d_in[4];
    const float* ew1 = (const float*)d_in[5];
    const float* eb1 = (const float*)d_in[6];
    const float* ew2 = (const float*)d_in[7];
    const float* eb2 = (const float*)d_in[8];
    float* y = (float*)d_out;

    // ws layout (403 MB + meta), aliased by liveness:
    //   [0,256MiB)       h1 f32 [16384][4096]  -> later hexp bf16 [8][4096][4096]
    //   [256MiB,352MiB)  A' bf16 [16384][3072] (router) -> later disp/eo bf16 (64MiB)
    //   [352MiB,376MiB)  B' bf16 [4096][3072]  (router)
    //   [320MiB,384MiB)  BTW bf16 (expert weights, written AFTER router GEMM)
    //   [384MiB,...)     ids / probs / pos (128KB each)
    char* ws = (char*)d_ws;
    float*          h1    = (float*)ws;
    unsigned short* hexp  = (unsigned short*)ws;
    unsigned short* A2    = (unsigned short*)(ws + 268435456L);   // 96 MiB
    unsigned short* B2    = (unsigned short*)(ws + 369098752L);   // 24 MiB
    unsigned short* disp  = (unsigned short*)(ws + 268435456L);
    unsigned short* eo    = (unsigned short*)(ws + 268435456L);
    unsigned short* BTW   = (unsigned short*)(ws + 335544320L);
    int*            ids   = (int*)  (ws + 402653184L);
    float*          probs = (float*)(ws + 402784256L);
    int*            pos   = (int*)  (ws + 402915328L);

    const size_t LDSB = 131072;   // 128 KiB ring-4 (1 block/CU — structural)

    // 1a) Build split operands for router GEMM1
    split_x<<<NTOK, 256, 0, stream>>>(x, A2);
    {
        dim3 g(H_ / 32, C_ / 32, 1);
        split_w<<<g, 256, 0, stream>>>(rw1, B2);
    }
    // 1b) Router GEMM1 on MFMA (split-bf16, ~fp32 exact):
    //     h1 = relu([x_hi|x_lo|x_hi] @ [w_hi;w_hi;w_lo] + rb1), fp32 out
    {
        dim3 g(H_ / 256, NTOK / 256, 1);   // 16 x 64
        gemm256_pipe<1, float><<<g, 512, LDSB, stream>>>(
            A2, B2, rb1, h1, KR_, H_, KR_ / 32, 0, 0, 0, 0);
    }
    // 2) Router GEMM2 + top-2 + softmax
    router_topk<<<NTOK, 256, 0, stream>>>(h1, rw2, rb2, ids, probs);
    // 3) Exact sequential capacity positions
    compute_pos<<<1, 256, 0, stream>>>(ids, pos);
    // 4) Dispatch tokens to expert buffers (bf16) — overwrites A' region (dead)
    dispatch_k<<<NSLOT, 256, 0, stream>>>(x, ids, pos, disp);
    // 5a) Convert+transpose ew1 [8][1024][4096] -> BT1 bf16 [8][4096][1024]
    {
        dim3 g(H_ / 32, C_ / 32, E_);
        transpose_cvt<<<g, 256, 0, stream>>>(ew1, BTW, C_, H_);
    }
    // 5b) Expert GEMM1 (MFMA): hexp = relu(disp @ ew1 + eb1)
    {
        dim3 g(H_ / 256, CAP_ / 256, E_);   // 16 x 16 x 8
        gemm256_pipe<1, unsigned short><<<g, 512, LDSB, stream>>>(
            disp, BTW, eb1, hexp, C_, H_, C_ / 32,
            (long)CAP_ * C_, (long)H_ * C_, (long)H_, (long)CAP_ * H_);
    }
    // 6a) Convert+transpose ew2 [8][4096][1024] -> BT2 bf16 [8][1024][4096]
    {
        dim3 g(C_ / 32, H_ / 32, E_);
        transpose_cvt<<<g, 256, 0, stream>>>(ew2, BTW, H_, C_);
    }
    // 6b) Expert GEMM2 (MFMA): eo = hexp @ ew2 + eb2   (bf16 out, gathered later)
    {
        dim3 g(C_ / 256, CAP_ / 256, E_);   // 4 x 16 x 8
        gemm256_pipe<0, unsigned short><<<g, 512, LDSB, stream>>>(
            hexp, BTW, eb2, eo, H_, C_, H_ / 32,
            (long)CAP_ * H_, (long)C_ * H_, (long)C_, (long)CAP_ * C_);
    }
    // 7) Combine: gather expert outputs, weight, sum (race-free, writes all of y)
    combine_k<<<NTOK, 256, 0, stream>>>(eo, ids, pos, probs, y);
}

// Round 9
// 1202.356 us; speedup vs baseline: 6.6325x; 1.0722x over previous
//
#include <hip/hip_runtime.h>
#include <cstdint>
#include <type_traits>

#define B_    8
#define T_    2048
#define C_    1024
#define E_    8
#define K_    2
#define CAP_  4096
#define H_    4096
#define NTOK  (B_ * T_)      // 16384
#define NSLOT (NTOK * K_)    // 32768
#define KR_   3072           // router split-GEMM K: [x_hi | x_lo | x_hi]

typedef __bf16 bf16x8 __attribute__((ext_vector_type(8)));
typedef float  f32x4  __attribute__((ext_vector_type(4)));

#define AS1 __attribute__((address_space(1)))
#define AS3 __attribute__((address_space(3)))

static __device__ __forceinline__ float b2f(unsigned short u) {
    union { float f; unsigned int i; } v; v.i = ((unsigned int)u) << 16; return v.f;
}
static __device__ __forceinline__ unsigned short f2b(float f) {
    unsigned int x = __float_as_uint(f);
    unsigned int r = (x + 0x7fffu + ((x >> 16) & 1u)) >> 16;   // RNE
    return (unsigned short)r;
}

template<int W> static __device__ __forceinline__ void vm_wait() {
    if constexpr (W == 4) asm volatile("s_waitcnt vmcnt(4)" ::: "memory");
    else if constexpr (W == 0) asm volatile("s_waitcnt vmcnt(0)" ::: "memory");
}

// ---------------------------------------------------------------------------
// 8-phase MFMA bf16 GEMM (m201-style): 256x256 tile, BK=64, 512 threads
// (8 waves 2Mx4N, wave tile 128x64), 2 LDS dbufs (2 x (A 32KB + B 32KB) =
// 128 KiB). Per K-tile kt (4 phases, each: reads -> stage -> barrier ->
// setprio(1) -> 16 MFMA -> setprio(0) -> barrier):
//   p0: ds A[mi0-3]kk0 + B[all]kk0 (8 reads); STAGE_A(kt+1)
//   p1: ds A[mi4-7]kk0 (4)
//   p2: ds A[mi0-3]kk1 + B[all]kk1 (8)
//   p3: ds A[mi4-7]kk1 (4); STAGE_B(kt+2); vmcnt(4)  [counted, never 0 mid-loop]
// WAR safety is deterministic: each phase's ds_reads are consumed by that
// phase's MFMAs (compiler lgkmcnt) before barrier2; the overwriting stage
// issues >=1 phase later. RAW: per-wave vmcnt(4) at p3 guarantees A(kt+1)
// and B(kt+1) landed (only B(kt+2)'s 4 loads outstanding).
// LDS swizzle (both sides): 16B-slot ^= row&7 (rows are 128B).
// NOTE: acc=128 VGPR + frags -> 2 waves/SIMD is structural; launch_bounds
// min-waves must stay 2 (round-7: 4 -> acc spilled, 6x slower).
// A [M][Kd] bf16 row-major, BT [N][Kd] bf16 (pre-transposed). Out [M][Nld].
// Requires M%256==0, N%256==0, Kd%64==0, NT=Kd/64 >= 2, grid.x*grid.y%8==0.
// ---------------------------------------------------------------------------
template<int RELU, typename TC>
__global__ __launch_bounds__(512, 2) void gemm256_8ph(
    const unsigned short* __restrict__ A, const unsigned short* __restrict__ BT,
    const float* __restrict__ bias, TC* __restrict__ Cout,
    int Kd, int Nld, int NT,
    long sA, long sB, long sBias, long sC)
{
    extern __shared__ char smem[];   // dbuf d: A at d*65536, B at d*65536+32768

    const int z = blockIdx.z;
    A    += (size_t)z * sA;
    BT   += (size_t)z * sB;
    bias += (size_t)z * sBias;
    Cout += (size_t)z * sC;

    // XCD-aware swizzle (nwg % 8 == 0 for all our grids)
    const int gx = gridDim.x;
    const int nwg = gx * gridDim.y;
    int wg = blockIdx.y * gx + blockIdx.x;
    wg = (wg & 7) * (nwg >> 3) + (wg >> 3);
    const int bm = (wg / gx) * 256;
    const int bn = (wg % gx) * 256;

    const int tid  = threadIdx.x;
    const int lane = tid & 63;
    const int wid  = tid >> 6;
    const int wrow = (wid >> 2) * 128;   // wave M offset (2 waves in M)
    const int wcol = (wid & 3) * 64;     // wave N offset (4 waves in N)
    const int fr = lane & 15;            // fragment row/col within 16
    const int fq = lane >> 4;            // k-chunk selector (0..3)

    const size_t rbA = (size_t)Kd * 2;   // row stride in bytes (A and BT)
    const char* Ag = (const char*)A  + (size_t)bm * rbA;
    const char* Bg = (const char*)BT + (size_t)bn * rbA;

    f32x4 acc[8][4];
#pragma unroll
    for (int i = 0; i < 8; i++)
#pragma unroll
        for (int j = 0; j < 4; j++) acc[i][j] = (f32x4){0.f, 0.f, 0.f, 0.f};

    // ---- stage K-tile kt's A (or B) tile: 256 rows x 128B = 32KB, 4 rounds
    // of global_load_lds (512 thr x 16B). Linear LDS dest; global SOURCE
    // pre-swizzled (slot ^= row&7) so swizzled ds_reads see linear data.
    auto STAGE_A = [&](int kt) {
        char* d = smem + (size_t)(kt & 1) * 65536;
        const size_t kb = (size_t)kt * 128;
#pragma unroll
        for (int r = 0; r < 4; ++r) {
            const int o    = r * 8192 + tid * 16;
            const int row  = o >> 7;
            const int slot = (o >> 4) & 7;
            const int ss   = (slot ^ (row & 7)) << 4;
            __builtin_amdgcn_global_load_lds(
                (const AS1 void*)(Ag + (size_t)row * rbA + kb + ss),
                (AS3 void*)(d + r * 8192 + wid * 1024), 16, 0, 0);
        }
    };
    auto STAGE_B = [&](int kt) {
        char* d = smem + (size_t)(kt & 1) * 65536 + 32768;
        const size_t kb = (size_t)kt * 128;
#pragma unroll
        for (int r = 0; r < 4; ++r) {
            const int o    = r * 8192 + tid * 16;
            const int row  = o >> 7;
            const int slot = (o >> 4) & 7;
            const int ss   = (slot ^ (row & 7)) << 4;
            __builtin_amdgcn_global_load_lds(
                (const AS1 void*)(Bg + (size_t)row * rbA + kb + ss),
                (AS3 void*)(d + r * 8192 + wid * 1024), 16, 0, 0);
        }
    };

    // ---- swizzled fragment reads (16B at slot kk*4+fq of a 128B row)
    auto LDA = [&](int kt, int mi, int kk) -> bf16x8 {
        const char* base = smem + (size_t)(kt & 1) * 65536;
        const int row  = wrow + mi * 16 + fr;
        const int slot = (kk * 4 + fq) ^ (row & 7);
        return *(const bf16x8*)(base + row * 128 + slot * 16);
    };
    auto LDB = [&](int kt, int ni, int kk) -> bf16x8 {
        const char* base = smem + (size_t)(kt & 1) * 65536 + 32768;
        const int row  = wcol + ni * 16 + fr;
        const int slot = (kk * 4 + fq) ^ (row & 7);
        return *(const bf16x8*)(base + row * 128 + slot * 16);
    };

    // ---- prologue: A0, B0, B1 staged (A1 staged in kt0-p0); tile-0 landed
    STAGE_A(0); STAGE_B(0); STAGE_B(1);
    vm_wait<4>();                       // A0+B0 landed; B1's 4 in flight
    __builtin_amdgcn_s_barrier();

    bf16x8 a[4], bb[4];
    for (int kt = 0; kt < NT; ++kt) {
        // ---------- p0: A[0-3]kk0 + B[all]kk0; stage A(kt+1)
#pragma unroll
        for (int i = 0; i < 4; ++i) a[i]  = LDA(kt, i, 0);
#pragma unroll
        for (int i = 0; i < 4; ++i) bb[i] = LDB(kt, i, 0);
        if (kt + 1 < NT) STAGE_A(kt + 1);
        __builtin_amdgcn_s_barrier();
        __builtin_amdgcn_s_setprio(1);
#pragma unroll
        for (int mi = 0; mi < 4; ++mi)
#pragma unroll
            for (int ni = 0; ni < 4; ++ni)
                acc[mi][ni] = __builtin_amdgcn_mfma_f32_16x16x32_bf16(
                    a[mi], bb[ni], acc[mi][ni], 0, 0, 0);
        __builtin_amdgcn_s_setprio(0);
        __builtin_amdgcn_s_barrier();
        // ---------- p1: A[4-7]kk0 (B kk0 still in regs)
#pragma unroll
        for (int i = 0; i < 4; ++i) a[i] = LDA(kt, 4 + i, 0);
        __builtin_amdgcn_s_barrier();
        __builtin_amdgcn_s_setprio(1);
#pragma unroll
        for (int mi = 0; mi < 4; ++mi)
#pragma unroll
            for (int ni = 0; ni < 4; ++ni)
                acc[4 + mi][ni] = __builtin_amdgcn_mfma_f32_16x16x32_bf16(
                    a[mi], bb[ni], acc[4 + mi][ni], 0, 0, 0);
        __builtin_amdgcn_s_setprio(0);
        __builtin_amdgcn_s_barrier();
        // ---------- p2: A[0-3]kk1 + B[all]kk1
#pragma unroll
        for (int i = 0; i < 4; ++i) a[i]  = LDA(kt, i, 1);
#pragma unroll
        for (int i = 0; i < 4; ++i) bb[i] = LDB(kt, i, 1);
        __builtin_amdgcn_s_barrier();
        __builtin_amdgcn_s_setprio(1);
#pragma unroll
        for (int mi = 0; mi < 4; ++mi)
#pragma unroll
            for (int ni = 0; ni < 4; ++ni)
                acc[mi][ni] = __builtin_amdgcn_mfma_f32_16x16x32_bf16(
                    a[mi], bb[ni], acc[mi][ni], 0, 0, 0);
        __builtin_amdgcn_s_setprio(0);
        __builtin_amdgcn_s_barrier();
        // ---------- p3: A[4-7]kk1; stage B(kt+2); counted vmcnt
#pragma unroll
        for (int i = 0; i < 4; ++i) a[i] = LDA(kt, 4 + i, 1);
        if (kt + 2 < NT) STAGE_B(kt + 2);
        if (kt + 1 < NT) {
            if (kt + 2 < NT) vm_wait<4>();   // A(kt+1),B(kt+1) landed
            else             vm_wait<0>();   // drain for last tile
        }
        __builtin_amdgcn_s_barrier();
        __builtin_amdgcn_s_setprio(1);
#pragma unroll
        for (int mi = 0; mi < 4; ++mi)
#pragma unroll
            for (int ni = 0; ni < 4; ++ni)
                acc[4 + mi][ni] = __builtin_amdgcn_mfma_f32_16x16x32_bf16(
                    a[mi], bb[ni], acc[4 + mi][ni], 0, 0, 0);
        __builtin_amdgcn_s_setprio(0);
        __builtin_amdgcn_s_barrier();
    }

    // ---- epilogue (16x16 C/D: col=lane&15, row=fq*4+reg — round-6 proven).
    // Opaque bias ptr so LICM can't hoist loads into the K-loop.
    const float* bias_o = bias;
    asm volatile("" : "+s"(bias_o));
#pragma unroll
    for (int mi = 0; mi < 8; ++mi) {
#pragma unroll
        for (int ni = 0; ni < 4; ++ni) {
            const int c = bn + wcol + ni * 16 + fr;
            const float bv = bias_o[c];
#pragma unroll
            for (int rg = 0; rg < 4; ++rg) {
                const int r = bm + wrow + mi * 16 + fq * 4 + rg;
                float v = acc[mi][ni][rg] + bv;
                if (RELU) v = fmaxf(v, 0.f);
                if constexpr (std::is_same_v<TC, float>)
                    Cout[(size_t)r * Nld + c] = v;
                else
                    Cout[(size_t)r * Nld + c] = f2b(v);
            }
        }
    }
}

// ---------------------------------------------------------------------------
// Split x (fp32) -> A' bf16 [NTOK][3072] = [x_hi | x_lo | x_hi]
// ---------------------------------------------------------------------------
__global__ __launch_bounds__(256) void split_x(
    const float* __restrict__ x, unsigned short* __restrict__ A2)
{
    const int n = blockIdx.x;
    const int c = threadIdx.x * 4;
    const float4 v = *(const float4*)(x + (size_t)n * C_ + c);
    ushort4 hi, lo;
    hi.x = f2b(v.x); lo.x = f2b(v.x - b2f(hi.x));
    hi.y = f2b(v.y); lo.y = f2b(v.y - b2f(hi.y));
    hi.z = f2b(v.z); lo.z = f2b(v.z - b2f(hi.z));
    hi.w = f2b(v.w); lo.w = f2b(v.w - b2f(hi.w));
    unsigned short* row = A2 + (size_t)n * KR_;
    *(ushort4*)(row + c)            = hi;
    *(ushort4*)(row + C_ + c)       = lo;
    *(ushort4*)(row + 2 * C_ + c)   = hi;
}

// ---------------------------------------------------------------------------
// Split+transpose rw1 [C][H] fp32 -> B'^T bf16 [H][3072] = [w_hi | w_hi | w_lo]
// ---------------------------------------------------------------------------
__global__ __launch_bounds__(256) void split_w(
    const float* __restrict__ in, unsigned short* __restrict__ out)
{
    __shared__ float t[32][33];
    const int rb = blockIdx.y * 32;   // c-dim tile
    const int cb = blockIdx.x * 32;   // h-dim tile
    const int tr = threadIdx.x >> 3, tc = (threadIdx.x & 7) * 4;
    const float4 v = *(const float4*)(in + (size_t)(rb + tr) * H_ + cb + tc);
    t[tr][tc + 0] = v.x; t[tr][tc + 1] = v.y; t[tr][tc + 2] = v.z; t[tr][tc + 3] = v.w;
    __syncthreads();
    ushort4 hi, lo;
    float f;
    f = t[tc + 0][tr]; hi.x = f2b(f); lo.x = f2b(f - b2f(hi.x));
    f = t[tc + 1][tr]; hi.y = f2b(f); lo.y = f2b(f - b2f(hi.y));
    f = t[tc + 2][tr]; hi.z = f2b(f); lo.z = f2b(f - b2f(hi.z));
    f = t[tc + 3][tr]; hi.w = f2b(f); lo.w = f2b(f - b2f(hi.w));
    unsigned short* row = out + (size_t)(cb + tr) * KR_;
    *(ushort4*)(row + rb + tc)           = hi;
    *(ushort4*)(row + C_ + rb + tc)      = hi;
    *(ushort4*)(row + 2 * C_ + rb + tc)  = lo;
}

// ---------------------------------------------------------------------------
// Tiled transpose + fp32->bf16 convert: in [z][R][Ncols] f32 -> out [z][Ncols][R] bf16
// ---------------------------------------------------------------------------
__global__ __launch_bounds__(256) void transpose_cvt(
    const float* __restrict__ in, unsigned short* __restrict__ out, int R, int Ncols)
{
    __shared__ float t[32][33];
    const size_t zoff = (size_t)blockIdx.z * R * Ncols;
    in  += zoff;
    out += zoff;
    const int rb = blockIdx.y * 32, cb = blockIdx.x * 32;
    const int tr = threadIdx.x >> 3, tc = (threadIdx.x & 7) * 4;
    const float4 v = *(const float4*)(in + (size_t)(rb + tr) * Ncols + cb + tc);
    t[tr][tc + 0] = v.x; t[tr][tc + 1] = v.y; t[tr][tc + 2] = v.z; t[tr][tc + 3] = v.w;
    __syncthreads();
    ushort4 u;
    u.x = f2b(t[tc + 0][tr]); u.y = f2b(t[tc + 1][tr]);
    u.z = f2b(t[tc + 2][tr]); u.w = f2b(t[tc + 3][tr]);
    *(ushort4*)(out + (size_t)(cb + tr) * R + rb + tc) = u;
}

// ---------------------------------------------------------------------------
// Router second GEMM (H x 8) + top-2 + softmax, fused. One block per token.
// ---------------------------------------------------------------------------
__global__ __launch_bounds__(256) void router_topk(
    const float* __restrict__ h1, const float* __restrict__ rw2,
    const float* __restrict__ rb2, int* __restrict__ ids, float* __restrict__ probs)
{
    const int n = blockIdx.x;
    const float* hrow = h1 + (size_t)n * H_;
    float acc[E_];
#pragma unroll
    for (int e = 0; e < E_; e++) acc[e] = 0.f;
    for (int h = threadIdx.x; h < H_; h += 256) {
        const float hv = hrow[h];
        const float4 w0 = *(const float4*)(rw2 + (size_t)h * E_);
        const float4 w1 = *(const float4*)(rw2 + (size_t)h * E_ + 4);
        acc[0] = fmaf(hv, w0.x, acc[0]); acc[1] = fmaf(hv, w0.y, acc[1]);
        acc[2] = fmaf(hv, w0.z, acc[2]); acc[3] = fmaf(hv, w0.w, acc[3]);
        acc[4] = fmaf(hv, w1.x, acc[4]); acc[5] = fmaf(hv, w1.y, acc[5]);
        acc[6] = fmaf(hv, w1.z, acc[6]); acc[7] = fmaf(hv, w1.w, acc[7]);
    }
    __shared__ float red[E_][256];
#pragma unroll
    for (int e = 0; e < E_; e++) red[e][threadIdx.x] = acc[e];
    __syncthreads();
    for (int st = 128; st > 0; st >>= 1) {
        if (threadIdx.x < st) {
#pragma unroll
            for (int e = 0; e < E_; e++) red[e][threadIdx.x] += red[e][threadIdx.x + st];
        }
        __syncthreads();
    }
    if (threadIdx.x == 0) {
        float v1 = -1e30f, v2 = -1e30f; int i1 = 0, i2 = 0;
#pragma unroll
        for (int e = 0; e < E_; e++) {
            const float v = red[e][0] + rb2[e];
            if (v > v1)      { v2 = v1; i2 = i1; v1 = v; i1 = e; }
            else if (v > v2) { v2 = v;  i2 = e; }
        }
        const float e2 = expf(v2 - v1);
        const float inv = 1.f / (1.f + e2);
        ids[n * 2] = i1;  ids[n * 2 + 1] = i2;
        probs[n * 2] = inv; probs[n * 2 + 1] = e2 * inv;
    }
}

// ---------------------------------------------------------------------------
// Exact sequential per-expert prefix count (reference cumsum semantics).
// ---------------------------------------------------------------------------
__global__ __launch_bounds__(256) void compute_pos(
    const int* __restrict__ ids, int* __restrict__ pos)
{
    __shared__ int hist[256][E_];
    const int t = threadIdx.x;
    const int per = NSLOT / 256;   // 128
    int cnt[E_];
#pragma unroll
    for (int e = 0; e < E_; e++) cnt[e] = 0;
    const int s0 = t * per;
    for (int i = 0; i < per; i++) cnt[ids[s0 + i]]++;
#pragma unroll
    for (int e = 0; e < E_; e++) hist[t][e] = cnt[e];
    __syncthreads();
    if (t < E_) {
        int run = 0;
        for (int i = 0; i < 256; i++) { const int c = hist[i][t]; hist[i][t] = run; run += c; }
    }
    __syncthreads();
    int run[E_];
#pragma unroll
    for (int e = 0; e < E_; e++) run[e] = hist[t][e];
    for (int i = 0; i < per; i++) { const int e = ids[s0 + i]; pos[s0 + i] = run[e]++; }
}

// ---------------------------------------------------------------------------
// Dispatch: copy kept tokens into per-expert buffers (bf16).
// ---------------------------------------------------------------------------
__global__ __launch_bounds__(256) void dispatch_k(
    const float* __restrict__ x, const int* __restrict__ ids,
    const int* __restrict__ pos, unsigned short* __restrict__ disp)
{
    const int s = blockIdx.x;
    const int e = ids[s], p = pos[s];
    if (p >= CAP_) return;                      // dropped over capacity
    const int n = s >> 1;                       // K_ == 2
    const float4 v = *(const float4*)(x + (size_t)n * C_ + threadIdx.x * 4);
    ushort4 u;
    u.x = f2b(v.x); u.y = f2b(v.y); u.z = f2b(v.z); u.w = f2b(v.w);
    *(ushort4*)(disp + ((size_t)e * CAP_ + p) * C_ + threadIdx.x * 4) = u;
}

// ---------------------------------------------------------------------------
// Combine (gather, race-free): y[n] = sum_k probs * eo[id_k, pos_k]
// ---------------------------------------------------------------------------
__global__ __launch_bounds__(256) void combine_k(
    const unsigned short* __restrict__ eo, const int* __restrict__ ids,
    const int* __restrict__ pos, const float* __restrict__ probs,
    float* __restrict__ y)
{
    const int n = blockIdx.x;
    const int c = threadIdx.x * 4;
    float r0 = 0.f, r1 = 0.f, r2 = 0.f, r3 = 0.f;
#pragma unroll
    for (int k = 0; k < K_; k++) {
        const int p = pos[2 * n + k];
        if (p >= CAP_) continue;
        const int e = ids[2 * n + k];
        const float w = probs[2 * n + k];
        const ushort4 u = *(const ushort4*)(eo + ((size_t)e * CAP_ + p) * C_ + c);
        r0 = fmaf(w, b2f(u.x), r0); r1 = fmaf(w, b2f(u.y), r1);
        r2 = fmaf(w, b2f(u.z), r2); r3 = fmaf(w, b2f(u.w), r3);
    }
    *(float4*)(y + (size_t)n * C_ + c) = make_float4(r0, r1, r2, r3);
}

// ---------------------------------------------------------------------------
extern "C" void kernel_launch(void* const* d_in, const int* in_sizes, int n_in,
                              void* d_out, int out_size, void* d_ws, size_t ws_size,
                              hipStream_t stream)
{
    const float* x   = (const float*)d_in[0];
    const float* rw1 = (const float*)d_in[1];
    const float* rb1 = (const float*)d_in[2];
    const float* rw2 = (const float*)d_in[3];
    const float* rb2 = (const float*)d_in[4];
    const float* ew1 = (const float*)d_in[5];
    const float* eb1 = (const float*)d_in[6];
    const float* ew2 = (const float*)d_in[7];
    const float* eb2 = (const float*)d_in[8];
    float* y = (float*)d_out;

    // ws layout (403 MB + meta), aliased by liveness:
    //   [0,256MiB)       h1 f32 [16384][4096]  -> later hexp bf16 [8][4096][4096]
    //   [256MiB,352MiB)  A' bf16 [16384][3072] (router) -> later disp/eo bf16 (64MiB)
    //   [352MiB,376MiB)  B' bf16 [4096][3072]  (router)
    //   [320MiB,384MiB)  BTW bf16 (expert weights, written AFTER router GEMM)
    //   [384MiB,...)     ids / probs / pos (128KB each)
    char* ws = (char*)d_ws;
    float*          h1    = (float*)ws;
    unsigned short* hexp  = (unsigned short*)ws;
    unsigned short* A2    = (unsigned short*)(ws + 268435456L);   // 96 MiB
    unsigned short* B2    = (unsigned short*)(ws + 369098752L);   // 24 MiB
    unsigned short* disp  = (unsigned short*)(ws + 268435456L);
    unsigned short* eo    = (unsigned short*)(ws + 268435456L);
    unsigned short* BTW   = (unsigned short*)(ws + 335544320L);
    int*            ids   = (int*)  (ws + 402653184L);
    float*          probs = (float*)(ws + 402784256L);
    int*            pos   = (int*)  (ws + 402915328L);

    const size_t LDSB = 131072;   // 128 KiB: 2 dbuf x (A 32K + B 32K)

    // 1a) Build split operands for router GEMM1
    split_x<<<NTOK, 256, 0, stream>>>(x, A2);
    {
        dim3 g(H_ / 32, C_ / 32, 1);
        split_w<<<g, 256, 0, stream>>>(rw1, B2);
    }
    // 1b) Router GEMM1 on MFMA (split-bf16, ~fp32 exact):
    //     h1 = relu([x_hi|x_lo|x_hi] @ [w_hi;w_hi;w_lo] + rb1), fp32 out
    {
        dim3 g(H_ / 256, NTOK / 256, 1);   // 16 x 64
        gemm256_8ph<1, float><<<g, 512, LDSB, stream>>>(
            A2, B2, rb1, h1, KR_, H_, KR_ / 64, 0, 0, 0, 0);
    }
    // 2) Router GEMM2 + top-2 + softmax
    router_topk<<<NTOK, 256, 0, stream>>>(h1, rw2, rb2, ids, probs);
    // 3) Exact sequential capacity positions
    compute_pos<<<1, 256, 0, stream>>>(ids, pos);
    // 4) Dispatch tokens to expert buffers (bf16) — overwrites A' region (dead)
    dispatch_k<<<NSLOT, 256, 0, stream>>>(x, ids, pos, disp);
    // 5a) Convert+transpose ew1 [8][1024][4096] -> BT1 bf16 [8][4096][1024]
    {
        dim3 g(H_ / 32, C_ / 32, E_);
        transpose_cvt<<<g, 256, 0, stream>>>(ew1, BTW, C_, H_);
    }
    // 5b) Expert GEMM1 (MFMA): hexp = relu(disp @ ew1 + eb1)
    {
        dim3 g(H_ / 256, CAP_ / 256, E_);   // 16 x 16 x 8
        gemm256_8ph<1, unsigned short><<<g, 512, LDSB, stream>>>(
            disp, BTW, eb1, hexp, C_, H_, C_ / 64,
            (long)CAP_ * C_, (long)H_ * C_, (long)H_, (long)CAP_ * H_);
    }
    // 6a) Convert+transpose ew2 [8][4096][1024] -> BT2 bf16 [8][1024][4096]
    {
        dim3 g(C_ / 32, H_ / 32, E_);
        transpose_cvt<<<g, 256, 0, stream>>>(ew2, BTW, H_, C_);
    }
    // 6b) Expert GEMM2 (MFMA): eo = hexp @ ew2 + eb2   (bf16 out, gathered later)
    {
        dim3 g(C_ / 256, CAP_ / 256, E_);   // 4 x 16 x 8
        gemm256_8ph<0, unsigned short><<<g, 512, LDSB, stream>>>(
            hexp, BTW, eb2, eo, H_, C_, H_ / 64,
            (long)CAP_ * H_, (long)C_ * H_, (long)C_, (long)CAP_ * C_);
    }
    // 7) Combine: gather expert outputs, weight, sum (race-free, writes all of y)
    combine_k<<<NTOK, 256, 0, stream>>>(eo, ids, pos, probs, y);
}